// Round 1
// baseline (7320.661 us; speedup 1.0000x reference)
//
#include <hip/hip_runtime.h>
#include <hip/hip_bf16.h>
#include <stdint.h>

#define NDIM   64     // node channels D
#define MDIM   16     // msg channels
#define NLAYER 3
#define EIN    129    // 2D+1
#define EHD    258    // edge hidden
#define CHD    64     // coord hidden
#define NHD    128    // node hidden
#define NIN    80     // D + M
#define ABSTR  528    // AB row stride (elems). A' in [0,264), B in [264,528)
#define AHALF  264

__device__ __forceinline__ float silu_f(float v) {
    return v / (1.0f + __expf(-v));
}
__device__ __forceinline__ float bflo(uint32_t u) {
    union { uint32_t u; float f; } c; c.u = u << 16; return c.f;
}
__device__ __forceinline__ float bfhi(uint32_t u) {
    union { uint32_t u; float f; } c; c.u = u & 0xffff0000u; return c.f;
}
__device__ __forceinline__ uint32_t f2bf_rne(float f) {
    uint32_t u = __float_as_uint(f);
    return (u + 0x7fffu + ((u >> 16) & 1u)) >> 16;
}

// ---------------- prep: transpose / pad weights once per call ----------------
// Wtg layout: [l][jg(66)][k(64)][i(8)]  value = Wcol(j=jg*8+i, k)
//   Wcol(j,k) = We1[l][k][j]           for j < 258
//             = We1[l][64+k][j-264]    for 264 <= j < 522
//             = 0                      otherwise (padding)
// biasAB[l][j] = be1[l][j] for j<258 else 0
// Wn1t[l][j][k] = Wn1[l][k][j]   (j<128, k<80)
__global__ void prep_kernel(const float* __restrict__ We1, const float* __restrict__ be1,
                            const float* __restrict__ Wn1,
                            float* __restrict__ Wtg, float* __restrict__ biasAB,
                            float* __restrict__ Wn1t) {
    int idx = blockIdx.x * 256 + threadIdx.x;
    const int wtg_total = NLAYER * 66 * 64 * 8;   // 101376
    if (idx < wtg_total) {
        int l  = idx / 33792;
        int r  = idx % 33792;
        int jg = r / 512;
        int k  = (r % 512) / 8;
        int i  = r % 8;
        int j  = jg * 8 + i;
        float v = 0.f;
        if (j < EHD)                       v = We1[((size_t)l * EIN + k) * EHD + j];
        else if (j >= AHALF && j < AHALF + EHD)
                                           v = We1[((size_t)l * EIN + 64 + k) * EHD + (j - AHALF)];
        Wtg[idx] = v;
        return;
    }
    int idx2 = idx - wtg_total;
    if (idx2 < NLAYER * ABSTR) {
        int l = idx2 / ABSTR, j = idx2 % ABSTR;
        biasAB[idx2] = (j < EHD) ? be1[l * EHD + j] : 0.f;
        return;
    }
    int idx3 = idx2 - NLAYER * ABSTR;
    if (idx3 < NLAYER * NHD * NIN) {
        int l = idx3 / (NHD * NIN);
        int r = idx3 % (NHD * NIN);
        int j = r / NIN;
        int k = r % NIN;
        Wn1t[idx3] = Wn1[((size_t)l * NIN + k) * NHD + j];
    }
}

// ---------------- init: embedding lookup + pos copy ----------------
__global__ void init_kernel(const int* __restrict__ feats, const float* __restrict__ coors,
                            const float* __restrict__ emb,
                            float* __restrict__ x, float* __restrict__ pos, int N) {
    int idx = blockIdx.x * 256 + threadIdx.x;
    int nx = N * NDIM;
    if (idx < nx) {
        int n = idx >> 6, c = idx & 63;
        x[idx] = emb[feats[n] * NDIM + c];
    } else {
        int j = idx - nx;
        if (j < N * 3) pos[j] = coors[j];
    }
}

// ---------------- per-node AB GEMM: AB[n] = [x@We1_top + be1 | x@We1_bot] (bf16) ----------
__global__ void __launch_bounds__(256) gemm_ab_kernel(
        const float* __restrict__ x, const float* __restrict__ Wtg,
        const float* __restrict__ biasAB, uint16_t* __restrict__ AB, int N) {
    int n = blockIdx.x * 256 + threadIdx.x;
    if (n >= N) return;
    float xr[64];
    const float4* xp = (const float4*)(x + (size_t)n * NDIM);
    #pragma unroll
    for (int q = 0; q < 16; ++q) {
        float4 v = xp[q];
        xr[4*q] = v.x; xr[4*q+1] = v.y; xr[4*q+2] = v.z; xr[4*q+3] = v.w;
    }
    uint16_t* out = AB + (size_t)n * ABSTR;
    for (int jg = 0; jg < 66; ++jg) {
        float acc[8];
        #pragma unroll
        for (int i = 0; i < 8; ++i) acc[i] = biasAB[jg * 8 + i];
        const float4* wp = (const float4*)(Wtg + (size_t)jg * 512);
        #pragma unroll
        for (int k = 0; k < 64; ++k) {        // full unroll -> xr[k] static
            float4 w0 = wp[2*k], w1 = wp[2*k+1];
            float xv = xr[k];
            acc[0] += xv * w0.x; acc[1] += xv * w0.y; acc[2] += xv * w0.z; acc[3] += xv * w0.w;
            acc[4] += xv * w1.x; acc[5] += xv * w1.y; acc[6] += xv * w1.z; acc[7] += xv * w1.w;
        }
        uint4 pk;
        pk.x = f2bf_rne(acc[0]) | (f2bf_rne(acc[1]) << 16);
        pk.y = f2bf_rne(acc[2]) | (f2bf_rne(acc[3]) << 16);
        pk.z = f2bf_rne(acc[4]) | (f2bf_rne(acc[5]) << 16);
        pk.w = f2bf_rne(acc[6]) | (f2bf_rne(acc[7]) << 16);
        *(uint4*)(out + jg * 8) = pk;
    }
}

// ---------------- per-edge fused message + coord + scatter ----------------
__global__ void __launch_bounds__(256) edge_kernel(
        const int* __restrict__ ei, const float* __restrict__ pos,
        const uint16_t* __restrict__ AB,
        const float* __restrict__ We2, const float* __restrict__ be2,
        const float* __restrict__ Wc1, const float* __restrict__ bc1,
        const float* __restrict__ Wc2, const float* __restrict__ bc2,
        const float* __restrict__ w128,
        float* __restrict__ agg_msg, float* __restrict__ agg_pos, int E) {

    __shared__ __align__(16) float We2s[AHALF * MDIM];   // [264][16]
    __shared__ __align__(16) float w128s[AHALF];
    __shared__ __align__(16) float Wc1s[MDIM * CHD];     // [16][64]
    __shared__ float bc1s[CHD];
    __shared__ float Wc2s[CHD];
    __shared__ float be2s[MDIM];
    __shared__ float bc2s;

    for (int i = threadIdx.x; i < AHALF * MDIM; i += 256)
        We2s[i] = (i < EHD * MDIM) ? We2[i] : 0.f;
    for (int i = threadIdx.x; i < AHALF; i += 256)
        w128s[i] = (i < EHD) ? w128[i] : 0.f;
    for (int i = threadIdx.x; i < MDIM * CHD; i += 256)
        Wc1s[i] = Wc1[i];
    if (threadIdx.x < CHD) { bc1s[threadIdx.x] = bc1[threadIdx.x]; Wc2s[threadIdx.x] = Wc2[threadIdx.x]; }
    if (threadIdx.x < MDIM) be2s[threadIdx.x] = be2[threadIdx.x];
    if (threadIdx.x == 0) bc2s = bc2[0];
    __syncthreads();

    int e = blockIdx.x * 256 + threadIdx.x;
    if (e >= E) return;
    int s = ei[e];
    int t = ei[E + e];

    float rx = pos[3*t]   - pos[3*s];
    float ry = pos[3*t+1] - pos[3*s+1];
    float rz = pos[3*t+2] - pos[3*s+2];
    float d2 = rx*rx + ry*ry + rz*rz;

    const uint4* arow = (const uint4*)(AB + (size_t)t * ABSTR);          // A' (tgt)
    const uint4* brow = (const uint4*)(AB + (size_t)s * ABSTR + AHALF);  // B  (src)

    float msg[MDIM];
    #pragma unroll
    for (int m = 0; m < MDIM; ++m) msg[m] = be2s[m];

    for (int kc = 0; kc < 33; ++kc) {     // 33 * 8 = 264 k values
        uint4 a = arow[kc], b = brow[kc];
        uint32_t au[4] = {a.x, a.y, a.z, a.w};
        uint32_t bu[4] = {b.x, b.y, b.z, b.w};
        #pragma unroll
        for (int q = 0; q < 4; ++q) {
            int k0 = kc * 8 + q * 2;
            float h0 = silu_f(bflo(au[q]) + bflo(bu[q]) + d2 * w128s[k0]);
            float h1 = silu_f(bfhi(au[q]) + bfhi(bu[q]) + d2 * w128s[k0 + 1]);
            const float4* w2v = (const float4*)&We2s[k0 * MDIM];
            float4 wa0 = w2v[0], wa1 = w2v[1], wa2 = w2v[2], wa3 = w2v[3];
            float4 wb0 = w2v[4], wb1 = w2v[5], wb2 = w2v[6], wb3 = w2v[7];
            msg[0]  += h0*wa0.x + h1*wb0.x;  msg[1]  += h0*wa0.y + h1*wb0.y;
            msg[2]  += h0*wa0.z + h1*wb0.z;  msg[3]  += h0*wa0.w + h1*wb0.w;
            msg[4]  += h0*wa1.x + h1*wb1.x;  msg[5]  += h0*wa1.y + h1*wb1.y;
            msg[6]  += h0*wa1.z + h1*wb1.z;  msg[7]  += h0*wa1.w + h1*wb1.w;
            msg[8]  += h0*wa2.x + h1*wb2.x;  msg[9]  += h0*wa2.y + h1*wb2.y;
            msg[10] += h0*wa2.z + h1*wb2.z;  msg[11] += h0*wa2.w + h1*wb2.w;
            msg[12] += h0*wa3.x + h1*wb3.x;  msg[13] += h0*wa3.y + h1*wb3.y;
            msg[14] += h0*wa3.z + h1*wb3.z;  msg[15] += h0*wa3.w + h1*wb3.w;
        }
    }
    #pragma unroll
    for (int m = 0; m < MDIM; ++m) msg[m] = silu_f(msg[m]);

    float cw = bc2s;
    #pragma unroll 4
    for (int c = 0; c < CHD; ++c) {
        float tacc = bc1s[c];
        #pragma unroll
        for (int m = 0; m < MDIM; ++m) tacc += msg[m] * Wc1s[m * CHD + c];
        cw += silu_f(tacc) * Wc2s[c];
    }

    float* am = agg_msg + (size_t)t * MDIM;
    #pragma unroll
    for (int m = 0; m < MDIM; ++m) atomicAdd(&am[m], msg[m]);
    atomicAdd(&agg_pos[3*t],   rx * cw);
    atomicAdd(&agg_pos[3*t+1], ry * cw);
    atomicAdd(&agg_pos[3*t+2], rz * cw);
}

// ---------------- per-node MLP + residual + pos update ----------------
__global__ void __launch_bounds__(256) node_kernel(
        float* __restrict__ x, float* __restrict__ pos,
        const float* __restrict__ agg_msg, const float* __restrict__ agg_pos,
        const float* __restrict__ Wn1t, const float* __restrict__ bn1,
        const float* __restrict__ Wn2, const float* __restrict__ bn2, int N) {
    int n = blockIdx.x * 256 + threadIdx.x;
    if (n >= N) return;
    float in[NIN];
    const float4* xp = (const float4*)(x + (size_t)n * NDIM);
    #pragma unroll
    for (int q = 0; q < 16; ++q) {
        float4 v = xp[q];
        in[4*q] = v.x; in[4*q+1] = v.y; in[4*q+2] = v.z; in[4*q+3] = v.w;
    }
    const float4* mp = (const float4*)(agg_msg + (size_t)n * MDIM);
    #pragma unroll
    for (int q = 0; q < 4; ++q) {
        float4 v = mp[q];
        in[64+4*q] = v.x; in[64+4*q+1] = v.y; in[64+4*q+2] = v.z; in[64+4*q+3] = v.w;
    }
    float out[NDIM];
    #pragma unroll
    for (int o = 0; o < NDIM; ++o) out[o] = bn2[o];
    for (int j = 0; j < NHD; ++j) {
        float t = bn1[j];
        const float4* w1 = (const float4*)(Wn1t + (size_t)j * NIN);
        #pragma unroll
        for (int q = 0; q < 20; ++q) {   // 80 = 20*4, full unroll -> in[] static
            float4 w = w1[q];
            t += in[4*q]*w.x + in[4*q+1]*w.y + in[4*q+2]*w.z + in[4*q+3]*w.w;
        }
        float h = silu_f(t);
        const float4* w2 = (const float4*)(Wn2 + (size_t)j * NDIM);
        #pragma unroll
        for (int q = 0; q < 16; ++q) {
            float4 w = w2[q];
            out[4*q] += h*w.x; out[4*q+1] += h*w.y; out[4*q+2] += h*w.z; out[4*q+3] += h*w.w;
        }
    }
    float4* xo = (float4*)(x + (size_t)n * NDIM);
    #pragma unroll
    for (int q = 0; q < 16; ++q) {
        float4 v;
        v.x = in[4*q]   + out[4*q];
        v.y = in[4*q+1] + out[4*q+1];
        v.z = in[4*q+2] + out[4*q+2];
        v.w = in[4*q+3] + out[4*q+3];
        xo[q] = v;
    }
    pos[3*n]   += agg_pos[3*n];
    pos[3*n+1] += agg_pos[3*n+1];
    pos[3*n+2] += agg_pos[3*n+2];
}

// ---------------- host launch ----------------
extern "C" void kernel_launch(void* const* d_in, const int* in_sizes, int n_in,
                              void* d_out, int out_size, void* d_ws, size_t ws_size,
                              hipStream_t stream) {
    const int*   feats = (const int*)  d_in[0];
    const float* coors = (const float*)d_in[1];
    const int*   ei    = (const int*)  d_in[2];
    const float* emb   = (const float*)d_in[3];
    const float* We1   = (const float*)d_in[4];
    const float* be1   = (const float*)d_in[5];
    const float* We2   = (const float*)d_in[6];
    const float* be2   = (const float*)d_in[7];
    const float* Wc1   = (const float*)d_in[8];
    const float* bc1   = (const float*)d_in[9];
    const float* Wc2   = (const float*)d_in[10];
    const float* bc2   = (const float*)d_in[11];
    const float* Wn1   = (const float*)d_in[12];
    const float* bn1   = (const float*)d_in[13];
    const float* Wn2   = (const float*)d_in[14];
    const float* bn2   = (const float*)d_in[15];

    const int N = in_sizes[0];
    const int E = in_sizes[2] / 2;

    float* x   = (float*)d_out;                 // [N,64]
    float* pos = (float*)d_out + (size_t)N * NDIM;  // [N,3]

    // workspace layout
    char* w = (char*)d_ws;
    uint16_t* AB = (uint16_t*)w;                       // N*528 bf16
    size_t off = ((size_t)N * ABSTR * 2 + 255) & ~(size_t)255;
    float* agg_msg = (float*)(w + off);                // N*16
    off += ((size_t)N * MDIM * 4 + 255) & ~(size_t)255;
    float* agg_pos = (float*)(w + off);                // N*3
    off += ((size_t)N * 3 * 4 + 255) & ~(size_t)255;
    float* Wtg = (float*)(w + off);                    // 3*66*64*8 f32
    off += (size_t)NLAYER * 33792 * 4;
    float* biasAB = (float*)(w + off);                 // 3*528
    off += (size_t)NLAYER * ABSTR * 4;
    float* Wn1t = (float*)(w + off);                   // 3*128*80
    (void)ws_size; (void)n_in; (void)out_size;

    // prep (all layers)
    {
        int total = NLAYER * 33792 + NLAYER * ABSTR + NLAYER * NHD * NIN;
        prep_kernel<<<(total + 255) / 256, 256, 0, stream>>>(We1, be1, Wn1, Wtg, biasAB, Wn1t);
    }
    // init x, pos
    {
        int total = N * (NDIM + 3);
        init_kernel<<<(total + 255) / 256, 256, 0, stream>>>(feats, coors, emb, x, pos, N);
    }

    for (int l = 0; l < NLAYER; ++l) {
        const float* We1_l  = We1 + (size_t)l * EIN * EHD;
        const float* w128_l = We1_l + (size_t)128 * EHD;

        gemm_ab_kernel<<<(N + 255) / 256, 256, 0, stream>>>(
            x, Wtg + (size_t)l * 33792, biasAB + (size_t)l * ABSTR, AB, N);

        hipMemsetAsync(agg_msg, 0, (size_t)N * MDIM * 4, stream);
        hipMemsetAsync(agg_pos, 0, (size_t)N * 3 * 4, stream);

        edge_kernel<<<(E + 255) / 256, 256, 0, stream>>>(
            ei, pos, AB,
            We2 + (size_t)l * EHD * MDIM, be2 + (size_t)l * MDIM,
            Wc1 + (size_t)l * MDIM * CHD, bc1 + (size_t)l * CHD,
            Wc2 + (size_t)l * CHD, bc2 + l, w128_l,
            agg_msg, agg_pos, E);

        node_kernel<<<(N + 255) / 256, 256, 0, stream>>>(
            x, pos, agg_msg, agg_pos,
            Wn1t + (size_t)l * NHD * NIN, bn1 + (size_t)l * NHD,
            Wn2 + (size_t)l * NHD * NDIM, bn2 + (size_t)l * NDIM, N);
    }
}